// Round 1
// 488.652 us; speedup vs baseline: 1.0512x; 1.0512x over previous
//
#include <hip/hip_runtime.h>
#include <math.h>

#define D_IN 256
#define HID  128
#define NQ   4
#define NPB  8   // nodes per block

// ---------------- quantum statevector gates (compile-time qubit masks) -------
// Templated on qubit index so every re[]/im[] index is compile-time constant
// => statevector stays in VGPRs (no scratch; see rule: runtime-indexed arrays
// spill to local memory).

template<int Q>
__device__ __forceinline__ void ry16(float re[16], float im[16], float t) {
    float c = cosf(0.5f * t), s = sinf(0.5f * t);
    #pragma unroll
    for (int i = 0; i < 16; ++i) {
        if (i & (1 << Q)) continue;
        const int i1 = i | (1 << Q);
        float r0 = re[i], m0 = im[i], r1 = re[i1], m1 = im[i1];
        re[i]  = c * r0 - s * r1;  im[i]  = c * m0 - s * m1;
        re[i1] = s * r0 + c * r1;  im[i1] = s * m0 + c * m1;
    }
}

template<int Q>
__device__ __forceinline__ void rz16(float re[16], float im[16], float t) {
    float c = cosf(0.5f * t), s = sinf(0.5f * t);
    #pragma unroll
    for (int i = 0; i < 16; ++i) {
        float r = re[i], mm = im[i];
        if (i & (1 << Q)) { re[i] = r * c - mm * s; im[i] = mm * c + r * s; }   // e^{+it/2}
        else              { re[i] = r * c + mm * s; im[i] = mm * c - r * s; }   // e^{-it/2}
    }
}

template<int C, int T>
__device__ __forceinline__ void cx16(float re[16], float im[16]) {
    #pragma unroll
    for (int i = 0; i < 16; ++i) {
        if ((i & (1 << C)) && !(i & (1 << T))) {
            const int i1 = i | (1 << T);
            float r  = re[i]; re[i] = re[i1]; re[i1] = r;
            float mm = im[i]; im[i] = im[i1]; im[i1] = mm;
        }
    }
}

// ---------------- fully fused kernel -----------------------------------------
// Per block: 8 nodes, 128 threads (thread j = output column j).
// Wave 0 stages X; lanes 64..67 (wave 1) concurrently simulate the 2-layer
// 4-qubit circuit on basis states e_0..e_3 to build M4 = Re(U[0:4,0:4]).
// Then: enc L1 (256->128, relu) -> enc L2 (128->4) -> triple-normalize ->
// t = M4 @ s4 (4x4) -> dec L1 h = relu(t @ Wd1 + bd1) -> dec L2 (128->128).
// No workspace, no second kernel.

__global__ __launch_bounds__(128) void fused_gnn_kernel(
    const float* __restrict__ X,
    const float* __restrict__ We1, const float* __restrict__ be1,
    const float* __restrict__ We2, const float* __restrict__ be2,
    const float* __restrict__ mp,  const float* __restrict__ Wd1,
    const float* __restrict__ bd1,
    const float* __restrict__ Wd2, const float* __restrict__ bd2,
    float* __restrict__ out, int N)
{
    __shared__ float Xs[NPB][D_IN + 4];   // row stride 260 floats (16B multiple)
    __shared__ float hs[NPB][HID + 4];    // reused: h1 then h
    __shared__ float qs[NPB][4];
    __shared__ float t4s[NPB][4];         // t = M4 @ s4 per node
    __shared__ float M4s[4][4];           // M4[row j][basis b]

    const int j  = threadIdx.x;           // 0..127
    const int n0 = blockIdx.x * NPB;

    // ---- wave 0: stage X rows into LDS (float4, coalesced) ----
    if (j < 64) {
        for (int idx = j; idx < NPB * (D_IN / 4); idx += 64) {
            int n  = idx / (D_IN / 4);
            int kk = (idx % (D_IN / 4)) * 4;
            float4 v = make_float4(0.f, 0.f, 0.f, 0.f);
            if (n0 + n < N) v = *(const float4*)(X + (size_t)(n0 + n) * D_IN + kk);
            *(float4*)&Xs[n][kk] = v;
        }
    }
    // ---- wave 1, lanes 64..67: statevector sim of basis state b = j-64 ----
    if (j >= 64 && j < 68) {
        const int b = j - 64;
        float re[16], im[16];
        #pragma unroll
        for (int i = 0; i < 16; ++i) { re[i] = 0.f; im[i] = 0.f; }
        re[b] = 1.f;
        for (int L = 0; L < 2; ++L) {
            const float* th = mp + 12 * L;
            ry16<0>(re, im, th[0]);  ry16<1>(re, im, th[3]);
            ry16<2>(re, im, th[6]);  ry16<3>(re, im, th[9]);
            cx16<0, 1>(re, im); cx16<1, 2>(re, im); cx16<2, 3>(re, im);
            rz16<0>(re, im, th[1]);  rz16<1>(re, im, th[4]);
            rz16<2>(re, im, th[7]);  rz16<3>(re, im, th[10]);
            cx16<1, 2>(re, im);      // odd-pair CX for n_qubits=4
            ry16<0>(re, im, th[2]);  ry16<1>(re, im, th[5]);
            ry16<2>(re, im, th[8]);  ry16<3>(re, im, th[11]);
        }
        M4s[0][b] = re[0]; M4s[1][b] = re[1];
        M4s[2][b] = re[2]; M4s[3][b] = re[3];
    }
    __syncthreads();

    // ---- encoder layer 1: h1[n][j] = relu(X[n] . We1[:,j] + be1[j]) ----
    float acc[NPB];
    {
        float b1 = be1[j];
        #pragma unroll
        for (int n = 0; n < NPB; ++n) acc[n] = b1;
    }
    for (int k = 0; k < D_IN; k += 4) {
        float w0 = We1[(k + 0) * HID + j];
        float w1 = We1[(k + 1) * HID + j];
        float w2 = We1[(k + 2) * HID + j];
        float w3 = We1[(k + 3) * HID + j];
        #pragma unroll
        for (int n = 0; n < NPB; ++n) {
            float4 x = *(const float4*)&Xs[n][k];   // wave-broadcast LDS read
            acc[n] = fmaf(x.x, w0, acc[n]);
            acc[n] = fmaf(x.y, w1, acc[n]);
            acc[n] = fmaf(x.z, w2, acc[n]);
            acc[n] = fmaf(x.w, w3, acc[n]);
        }
    }
    #pragma unroll
    for (int n = 0; n < NPB; ++n) hs[n][j] = fmaxf(acc[n], 0.f);
    __syncthreads();

    // ---- encoder layer 2: qf[n][c] = h1[n] . We2[:,c] + be2[c]  (32 threads) ----
    if (j < NPB * 4) {
        int n = j >> 2, c = j & 3;
        float a = be2[c];
        #pragma unroll 8
        for (int k = 0; k < HID; ++k) a = fmaf(hs[n][k], We2[k * 4 + c], a);
        qs[n][c] = a;
    }
    __syncthreads();

    // ---- triple normalization + 4x4 quantum fold: t = M4 @ s4 ----
    if (j < NPB) {
        float q0 = qs[j][0], q1 = qs[j][1], q2 = qs[j][2], q3 = qs[j][3];
        float nn  = sqrtf(q0 * q0 + q1 * q1 + q2 * q2 + q3 * q3);
        float inv = 1.f / (nn + 1e-8f);
        q0 *= inv; q1 *= inv; q2 *= inv; q3 *= inv;
        nn  = sqrtf(q0 * q0 + q1 * q1 + q2 * q2 + q3 * q3);
        inv = 1.f / (nn + 1e-8f);
        q0 *= inv; q1 *= inv; q2 *= inv; q3 *= inv;
        nn  = sqrtf(q0 * q0 + q1 * q1 + q2 * q2 + q3 * q3);
        inv = 1.f / nn;
        q0 *= inv; q1 *= inv; q2 *= inv; q3 *= inv;
        #pragma unroll
        for (int r = 0; r < 4; ++r) {
            t4s[j][r] = M4s[r][0] * q0 + M4s[r][1] * q1
                      + M4s[r][2] * q2 + M4s[r][3] * q3;
        }
    }
    __syncthreads();

    // ---- decoder layer 1: h = relu(t @ Wd1 + bd1) ----
    float hv[NPB];
    {
        float w0 = Wd1[0 * HID + j], w1 = Wd1[1 * HID + j];
        float w2 = Wd1[2 * HID + j], w3 = Wd1[3 * HID + j];
        float bd = bd1[j];
        #pragma unroll
        for (int n = 0; n < NPB; ++n) {
            float a = bd;
            a = fmaf(t4s[n][0], w0, a);
            a = fmaf(t4s[n][1], w1, a);
            a = fmaf(t4s[n][2], w2, a);
            a = fmaf(t4s[n][3], w3, a);
            hv[n] = fmaxf(a, 0.f);
        }
    }
    __syncthreads();            // hs (h1) fully consumed; safe to overwrite
    #pragma unroll
    for (int n = 0; n < NPB; ++n) hs[n][j] = hv[n];
    __syncthreads();

    // ---- decoder layer 2: out[n][j] = h[n] . Wd2[:,j] + bd2[j] ----
    float o[NPB];
    {
        float b2 = bd2[j];
        #pragma unroll
        for (int n = 0; n < NPB; ++n) o[n] = b2;
    }
    for (int k = 0; k < HID; k += 4) {
        float w0 = Wd2[(k + 0) * HID + j];
        float w1 = Wd2[(k + 1) * HID + j];
        float w2 = Wd2[(k + 2) * HID + j];
        float w3 = Wd2[(k + 3) * HID + j];
        #pragma unroll
        for (int n = 0; n < NPB; ++n) {
            float4 h4 = *(const float4*)&hs[n][k];
            o[n] = fmaf(h4.x, w0, o[n]);
            o[n] = fmaf(h4.y, w1, o[n]);
            o[n] = fmaf(h4.z, w2, o[n]);
            o[n] = fmaf(h4.w, w3, o[n]);
        }
    }
    #pragma unroll
    for (int n = 0; n < NPB; ++n) {
        if (n0 + n < N) out[(size_t)(n0 + n) * HID + j] = o[n];
    }
}

// ---------------- launcher ---------------------------------------------------

extern "C" void kernel_launch(void* const* d_in, const int* in_sizes, int n_in,
                              void* d_out, int out_size, void* d_ws, size_t ws_size,
                              hipStream_t stream) {
    const float* X   = (const float*)d_in[0];
    // d_in[1] = adjacency: intentionally unused (reference ignores it).
    const float* We1 = (const float*)d_in[2];
    const float* be1 = (const float*)d_in[3];
    const float* We2 = (const float*)d_in[4];
    const float* be2 = (const float*)d_in[5];
    const float* mp  = (const float*)d_in[6];
    const float* Wd1 = (const float*)d_in[7];
    const float* bd1 = (const float*)d_in[8];
    const float* Wd2 = (const float*)d_in[9];
    const float* bd2 = (const float*)d_in[10];
    float* out = (float*)d_out;
    (void)d_ws; (void)ws_size;   // workspace intentionally untouched

    const int N = in_sizes[0] / D_IN;
    const int nblocks = (N + NPB - 1) / NPB;
    fused_gnn_kernel<<<nblocks, 128, 0, stream>>>(
        X, We1, be1, We2, be2, mp, Wd1, bd1, Wd2, bd2, out, N);
}